// Round 13
// baseline (436.253 us; speedup 1.0000x reference)
//
#include <hip/hip_runtime.h>
#include <hip/hip_bf16.h>
#include <math.h>

#define BB 8
#define NN 128
#define DD 256
#define HH 8
#define LL 4
#define FFD 1024
#define HD 32
#define NOBJ_ 150
#define NREL_ 51

typedef __attribute__((ext_vector_type(4))) float f32x4;
typedef __attribute__((ext_vector_type(8))) short s16x8;

__device__ __forceinline__ float erf_f(float x){
    float ax = fabsf(x);
    float t = __builtin_amdgcn_rcpf(1.f + 0.3275911f*ax);
    float y = t*(0.254829592f + t*(-0.284496736f + t*(1.421413741f +
              t*(-1.453152027f + t*1.061405429f))));
    float r = 1.f - y*__expf(-ax*ax);
    return copysignf(r, x);
}
__device__ __forceinline__ float gelu_f(float x){
    return 0.5f * x * (1.0f + erf_f(x * 0.70710678118654752f));
}
__device__ __forceinline__ ushort f2bf(float f){
    uint u = __float_as_uint(f);
    u += 0x7fff + ((u >> 16) & 1);
    return (ushort)(u >> 16);
}
__device__ __forceinline__ float bf2f(uint u){
    return __uint_as_float((u & 0xffffu) << 16);
}
// R19: async 16B global->LDS (no VGPR round-trip). Dest must be
// wave-uniform-base + lane*16 (our staging loops satisfy this: dest = gi*16,
// gi = tid + rr*256). Source is per-lane arbitrary.
__device__ __forceinline__ void gload16(const void* g, void* l){
    __builtin_amdgcn_global_load_lds(
        (const __attribute__((address_space(1))) uint*)g,
        (__attribute__((address_space(3))) uint*)l, 16, 0, 0);
}

// ---------------- fused LN + bf16 MFMA GEMM (M-tile 32, K=256 fixed) ----------------
// R19: WT is PRE-SWIZZLED (granule kq stored at kq^(n&7)); staging is a linear
// 32KB global_load_lds copy; the swizzled READ path is unchanged (XOR involution).
__global__ __launch_bounds__(256) void k_lngemm(
        const float* __restrict__ A, const float* __restrict__ gw,
        const float* __restrict__ bw, const ushort* __restrict__ WT,
        const float* __restrict__ bias, ushort* __restrict__ Cb,
        int Nc, int act){
    __shared__ __align__(16) ushort As[8192];    // 32 x 256 bf16, xor-swizzled
    __shared__ __align__(16) ushort Ws[16384];   // 64 x 256 bf16, pre-swizzled content
    int tid = threadIdx.x;
    int m0 = blockIdx.x*32, n0 = blockIdx.y*64;
    // issue W staging FIRST (async, fire-and-forget)
    {
        const ushort* wsrc = WT + (size_t)n0*256;
        #pragma unroll
        for (int rr = 0; rr < 8; rr++){
            int gi = tid + rr*256;
            gload16(wsrc + (size_t)gi*8, Ws + (size_t)gi*8);
        }
    }
    int r = tid >> 3, p = tid & 7;
    const float* ap = A + (size_t)(m0 + r)*256 + p*32;
    float x[32];
    float s1 = 0.f, s2 = 0.f;
    #pragma unroll
    for (int e4 = 0; e4 < 8; e4++){
        float4 v = *(const float4*)(ap + e4*4);
        x[e4*4+0]=v.x; x[e4*4+1]=v.y; x[e4*4+2]=v.z; x[e4*4+3]=v.w;
        s1 += v.x+v.y+v.z+v.w;
        s2 += v.x*v.x+v.y*v.y+v.z*v.z+v.w*v.w;
    }
    #pragma unroll
    for (int d = 1; d < 8; d <<= 1){
        s1 += __shfl_xor(s1, d, 64);
        s2 += __shfl_xor(s2, d, 64);
    }
    float mean = s1*(1.f/256.f);
    float var = s2*(1.f/256.f) - mean*mean;
    float rstd = rsqrtf(var + 1e-5f);
    #pragma unroll
    for (int j = 0; j < 4; j++){
        int kq = p*4 + j;
        uint o[4];
        #pragma unroll
        for (int pp = 0; pp < 4; pp++){
            int e = j*8 + pp*2;
            int k = p*32 + e;
            float v0 = (x[e]   - mean)*rstd*gw[k]   + bw[k];
            float v1 = (x[e+1] - mean)*rstd*gw[k+1] + bw[k+1];
            o[pp] = (uint)f2bf(v0) | ((uint)f2bf(v1) << 16);
        }
        int phys = r*32 + (kq ^ (r & 7));
        *(uint4*)(As + (size_t)phys*8) = make_uint4(o[0], o[1], o[2], o[3]);
    }
    __syncthreads();
    int lane = tid & 63, w = tid >> 6, l15 = lane & 15, q = lane >> 4;
    f32x4 acc[2];
    acc[0] = (f32x4){0.f,0.f,0.f,0.f};
    acc[1] = (f32x4){0.f,0.f,0.f,0.f};
    int m = (w&1)*16 + l15;
    #pragma unroll
    for (int k0 = 0; k0 < 8; k0++){
        int kq = k0*4 + q;
        s16x8 af = *(const s16x8*)(As + (size_t)(m*32 + (kq ^ (m&7)))*8);
        #pragma unroll
        for (int t = 0; t < 2; t++){
            int n = ((w>>1)*2 + t)*16 + l15;
            s16x8 bf = *(const s16x8*)(Ws + (size_t)(n*32 + (kq ^ (n&7)))*8);
            acc[t] = __builtin_amdgcn_mfma_f32_16x16x32_bf16(af, bf, acc[t], 0, 0, 0);
        }
    }
    int mb = (w&1)*16;
    #pragma unroll
    for (int t = 0; t < 2; t++){
        int n = n0 + ((w>>1)*2 + t)*16 + l15;
        if (n < Nc){
            float bv = bias ? bias[n] : 0.f;
            float vv[4] = {acc[t].x, acc[t].y, acc[t].z, acc[t].w};
            #pragma unroll
            for (int rr = 0; rr < 4; rr++){
                int m2 = m0 + mb + q*4 + rr;
                float v = vv[rr] + bv;
                if (act) v = gelu_f(v);
                Cb[(size_t)m2*Nc + n] = f2bf(v);
            }
        }
    }
}

// ---------------- BM=16 GEMM tile as device fn ----------------
// PRESWZ=true: W buffer is pre-swizzled -> stage via global_load_lds (linear dest).
// PRESWZ=false: raw W buffer -> old load + swizzled ds_write path.
// Read path identical in both cases (XOR involution).
template<bool PRESWZ>
__device__ __forceinline__ void dev_bgemm16(char* SMEM,
        const ushort* __restrict__ A, const ushort* __restrict__ WT,
        const float* __restrict__ bias, const float* __restrict__ R,
        float* __restrict__ C, ushort* __restrict__ Cb,
        int K, int Nc, int lda, int ldw, int ldc, int act, int m0, int n0){
    ushort* As = (ushort*)SMEM;           // 16x256 = 8 KB
    ushort* Ws = (ushort*)(SMEM + 8192);  // 64x256 = 32 KB
    int tid = threadIdx.x;
    int lane = tid & 63, w = tid >> 6;
    int l15 = lane & 15, q = lane >> 4;
    f32x4 acc = (f32x4){0.f,0.f,0.f,0.f};
    int m = l15;

    for (int kb = 0; kb < K; kb += 256){
        if (kb) __syncthreads();
        if (PRESWZ){
            #pragma unroll
            for (int rr = 0; rr < 8; rr++){
                int gi = tid + rr*256;
                int n = gi >> 5, kqs = gi & 31;
                gload16(WT + (size_t)(n0+n)*ldw + kb + kqs*8, Ws + (size_t)gi*8);
            }
        }
        #pragma unroll
        for (int rr = 0; rr < 2; rr++){
            int gi = tid + rr*256;
            int mm = gi >> 5, kq = gi & 31;
            uint4 v = *(const uint4*)(A + (size_t)(m0+mm)*lda + kb + kq*8);
            *(uint4*)(As + (size_t)(mm*32 + (kq ^ (mm&7)))*8) = v;
        }
        if (!PRESWZ){
            #pragma unroll
            for (int rr = 0; rr < 8; rr++){
                int gi = tid + rr*256;
                int n = gi >> 5, kq = gi & 31;
                uint4 v = *(const uint4*)(WT + (size_t)(n0+n)*ldw + kb + kq*8);
                *(uint4*)(Ws + (size_t)(n*32 + (kq ^ (n&7)))*8) = v;
            }
        }
        __syncthreads();
        #pragma unroll
        for (int k0 = 0; k0 < 8; k0++){
            int kq = k0*4 + q;
            s16x8 af = *(const s16x8*)(As + (size_t)(m*32 + (kq ^ (m&7)))*8);
            int n = w*16 + l15;
            s16x8 bf = *(const s16x8*)(Ws + (size_t)(n*32 + (kq ^ (n&7)))*8);
            acc = __builtin_amdgcn_mfma_f32_16x16x32_bf16(af, bf, acc, 0, 0, 0);
        }
    }
    {
        int n = n0 + w*16 + l15;
        if (n < Nc){
            float bv = bias ? bias[n] : 0.f;
            float vv[4] = {acc.x, acc.y, acc.z, acc.w};
            #pragma unroll
            for (int r = 0; r < 4; r++){
                int m2 = m0 + q*4 + r;
                float v = vv[r] + bv;
                if (act) v = gelu_f(v);
                size_t off = (size_t)m2*ldc + n;
                if (R) v += R[off];
                if (C) C[off] = v;
                if (Cb) Cb[off] = f2bf(v);
            }
        }
    }
}

// ---------------- generic bf16 MFMA GEMM (standalone, trunk; W pre-swizzled) ----------------
__global__ __launch_bounds__(256) void k_bgemm16(
        const ushort* __restrict__ A, const ushort* __restrict__ WT,
        const float* __restrict__ bias, const float* __restrict__ R,
        float* __restrict__ C, ushort* __restrict__ Cb,
        int K, int Nc, int lda, int ldw, int ldc, int act){
    __shared__ __align__(16) char SM[40960];
    dev_bgemm16<true>(SM, A, WT, bias, R, C, Cb, K, Nc, lda, ldw, ldc, act,
                      blockIdx.x*16, blockIdx.y*64);
}

// ---------------- attention (bf16 qkv in, bf16 out) — R15 LDS-halved, UNCHANGED ----------------
__global__ __launch_bounds__(256) void k_attn(const ushort* __restrict__ qkv,
        const int* __restrict__ rel_t, const float* __restrict__ relb,
        ushort* __restrict__ out){
    __shared__ float qs[32][33];
    __shared__ float ks[128][33];
    __shared__ float vs[128][36];
    __shared__ float S[32][129];
    __shared__ float red[32][8];
    __shared__ float rowmax[32], rowinv[32];
    int bid = blockIdx.x;
    int it = bid & 3, h = (bid >> 2) & 7, b = bid >> 5;
    int tid = threadIdx.x;
    int i0 = it*32;
    const float scale = 0.17677669529663687f;
    #pragma unroll
    for (int qq = 0; qq < 4; qq++){
        int e = tid + qq*256; int i = e >> 5, d = e & 31;
        qs[i][d] = bf2f(qkv[(size_t)(b*NN + i0 + i)*768 + h*HD + d]);
    }
    #pragma unroll
    for (int qq = 0; qq < 16; qq++){
        int e = tid + qq*256; int j = e >> 5, d = e & 31;
        ks[j][d] = bf2f(qkv[(size_t)(b*NN + j)*768 + 256 + h*HD + d]);
        vs[j][d] = bf2f(qkv[(size_t)(b*NN + j)*768 + 512 + h*HD + d]);
    }
    __syncthreads();
    int i = tid >> 3, s = tid & 7;
    {
        float qreg[32];
        #pragma unroll
        for (int kk = 0; kk < 32; kk++) qreg[kk] = qs[i][kk];
        for (int j = s; j < 128; j += 8){
            float acc = 0.f;
            #pragma unroll
            for (int kk = 0; kk < 32; kk++) acc += qreg[kk] * ks[j][kk];
            int r = rel_t[(size_t)(b*NN + i0 + i)*NN + j];
            S[i][j] = acc * scale + relb[r*HH + h];
        }
    }
    __syncthreads();
    float lm = -1e30f;
    for (int j = s; j < 128; j += 8) lm = fmaxf(lm, S[i][j]);
    red[i][s] = lm; __syncthreads();
    if (s == 0){
        float m = red[i][0];
        #pragma unroll
        for (int u = 1; u < 8; u++) m = fmaxf(m, red[i][u]);
        rowmax[i] = m;
    }
    __syncthreads();
    float rm = rowmax[i];
    float ls = 0.f;
    for (int j = s; j < 128; j += 8){ float e = __expf(S[i][j] - rm); S[i][j] = e; ls += e; }
    red[i][s] = ls; __syncthreads();
    if (s == 0){
        float sum = 0.f;
        #pragma unroll
        for (int u = 0; u < 8; u++) sum += red[i][u];
        rowinv[i] = 1.f / sum;
    }
    __syncthreads();
    {
        int d0 = s*4;
        float a0 = 0.f, a1 = 0.f, a2 = 0.f, a3 = 0.f;
        for (int j = 0; j < 128; j++){
            float p = S[i][j];
            float4 v4 = *(const float4*)&vs[j][d0];
            a0 += p*v4.x; a1 += p*v4.y; a2 += p*v4.z; a3 += p*v4.w;
        }
        float rinv = rowinv[i];
        size_t ob = (size_t)(b*NN + i0 + i)*DD + h*HD + d0;
        out[ob+0] = f2bf(a0 * rinv);
        out[ob+1] = f2bf(a1 * rinv);
        out[ob+2] = f2bf(a2 * rinv);
        out[ob+3] = f2bf(a3 * rinv);
    }
}

// ---------------- prep: pair-head weights + relbias + biascat + time MLP ----------------
// R19: wicatT now written PRE-SWIZZLED (kq ^ (c&7)). wjT stays raw (A operand).
__global__ __launch_bounds__(256) void k_prep_w(const float* __restrict__ eh1,
        const float* __restrict__ rh1, const float* __restrict__ rh_w2,
        const float* __restrict__ eh_b1, const float* __restrict__ rh_b1,
        const float* __restrict__ rel_emb, const float* __restrict__ eb_w,
        const float* __restrict__ eb_b,
        const int* __restrict__ t, const float* __restrict__ tw1,
        const float* __restrict__ tb1, const float* __restrict__ tw2,
        const float* __restrict__ tb2,
        ushort* __restrict__ w3fE, ushort* __restrict__ w3fR,
        ushort* __restrict__ wjT, ushort* __restrict__ w2fR,
        ushort* __restrict__ wicatT, float* __restrict__ biascat,
        float* __restrict__ relb, float* __restrict__ temb){
    __shared__ float t0[DD];
    __shared__ float y1[DD];
    if (blockIdx.x >= 207){                       // ---- time MLP blocks ----
        int b = blockIdx.x - 207, d = threadIdx.x;
        float tv = (float)t[b];
        float v;
        if (d < 128){
            float fr = expf(-9.210340371976184f * (float)d / 128.f);
            v = cosf(tv * fr);
        } else {
            float fr = expf(-9.210340371976184f * (float)(d - 128) / 128.f);
            v = sinf(tv * fr);
        }
        t0[d] = v; __syncthreads();
        float acc = tb1[d];
        for (int k = 0; k < DD; k++) acc += t0[k] * tw1[k*DD + d];
        acc = acc / (1.f + expf(-acc));
        y1[d] = acc; __syncthreads();
        float acc2 = tb2[d];
        for (int k = 0; k < DD; k++) acc2 += y1[k] * tw2[k*DD + d];
        temb[b*DD + d] = acc2;
        return;
    }
    int idx = blockIdx.x*256 + threadIdx.x;
    if (idx < 16384){
        int head = idx >> 13;                    // 0=E, 1=R
        int g = idx & 8191;
        int kc = g >> 11, rem = g & 2047;
        int CT = rem >> 7, ks = (rem >> 6) & 1, lane = rem & 63;
        int c = CT*16 + (lane & 15);
        const float* src = head ? rh1 : eh1;
        ushort* dst = head ? w3fR : w3fE;
        #pragma unroll
        for (int u = 0; u < 8; u++){
            int k = kc*64 + ks*32 + (lane >> 4)*8 + u;
            dst[(size_t)g*8 + u] = f2bf(src[(size_t)(768+k)*256 + c]);
        }
    } else if (idx < 32768){
        int g = idx - 16384;                     // wjT (A operand, raw layout)
        int c = g & 511, kq = g >> 9;            // kq 0..31
        size_t gidx = (size_t)c*32 + kq;
        #pragma unroll
        for (int u = 0; u < 8; u++){
            int k = kq*8 + u;
            float v = (c < 256) ? eh1[(size_t)(256+k)*256 + c] - eh1[(size_t)(512+k)*256 + c]
                                : rh1[(size_t)(256+k)*256 + (c-256)] - rh1[(size_t)(512+k)*256 + (c-256)];
            wjT[gidx*8 + u] = f2bf(v);
        }
    } else if (idx < 34816){
        int gg = idx - 32768;                    // w2fR 2048 granules
        int lane = gg & 63, rt = (gg >> 6) & 3, cs = (gg >> 8) & 3, g2 = gg >> 10;
        int r = rt*16 + (lane & 15);
        #pragma unroll
        for (int u = 0; u < 8; u++){
            int c = g2*128 + cs*32 + (lane >> 4)*8 + u;
            w2fR[(size_t)gg*8 + u] = (r < 50) ? f2bf(rh_w2[(size_t)c*50 + r]) : (ushort)0;
        }
    } else if (idx < 51200){
        int g = idx - 34816;                     // wicatT, PRE-SWIZZLED
        int c = g & 511, kq = g >> 9;
        size_t gidx = (size_t)c*32 + (kq ^ (c & 7));
        #pragma unroll
        for (int u = 0; u < 8; u++){
            int k = kq*8 + u;
            float v = (c < 256) ? eh1[(size_t)k*256 + c] + eh1[(size_t)(512+k)*256 + c]
                                : rh1[(size_t)k*256 + (c-256)] + rh1[(size_t)(512+k)*256 + (c-256)];
            wicatT[gidx*8 + u] = f2bf(v);
        }
    } else if (idx < 51328){
        int bg = idx - 51200;                    // biascat2 [1024]: eh_b1|rh_b1|0|0
        #pragma unroll
        for (int u = 0; u < 8; u++){
            int c = bg*8 + u;
            biascat[c] = (c < 256) ? eh_b1[c] : (c < 512) ? rh_b1[c-256] : 0.f;
        }
    } else if (idx < 52960){
        int t2 = idx - 51328;                    // relbias 4*51*8
        int l = t2 / (NREL_*HH);
        int rem = t2 - l*(NREL_*HH);
        int r = rem >> 3, h = rem & 7;
        float acc = eb_b[l*HH + h];
        for (int d = 0; d < DD; d++) acc += rel_emb[r*DD + d] * eb_w[(size_t)l*DD*HH + d*HH + h];
        relb[t2] = acc;
    }
}

// ---------------- prep: trunk/head weights -> transposed bf16, PRE-SWIZZLED ----------------
// R19: every W-panel buffer stores granule kq at position kq ^ (n&7) (within each
// 32-granule K-chunk), so GEMMs can stage with a linear global_load_lds while the
// swizzled read path stays identical (XOR is an involution).
__global__ __launch_bounds__(256) void k_prep_bw(
        const float* __restrict__ q_w, const float* __restrict__ k_w,
        const float* __restrict__ v_w, const float* __restrict__ o_w,
        const float* __restrict__ ff1, const float* __restrict__ ff2,
        const float* __restrict__ headw, const float* __restrict__ subjw,
        const float* __restrict__ objpw,
        const float* __restrict__ q_b, const float* __restrict__ k_b,
        const float* __restrict__ v_b,
        const float* __restrict__ subj_b, const float* __restrict__ objp_b,
        const int* __restrict__ obj_t, const float* __restrict__ obj_emb,
        const float* __restrict__ temb, float* __restrict__ hbuf,
        ushort* __restrict__ qkvT, ushort* __restrict__ oT,
        ushort* __restrict__ ff1T, ushort* __restrict__ ff2T,
        ushort* __restrict__ headT, ushort* __restrict__ sowT,
        float* __restrict__ qkvb, float* __restrict__ sob_b){
    if (blockIdx.x >= 1626){                     // ---- h init ----
        int idx = (blockIdx.x - 1626)*256 + threadIdx.x;
        int d = idx & 255, n = (idx >> 8) & 127, b = idx >> 15;
        int o = obj_t[b*NN + n];
        hbuf[idx] = obj_emb[o*DD + d] + temb[b*DD + d];
        return;
    }
    int g = blockIdx.x*256 + threadIdx.x;
    if (g < 98304){                                   // qkvT [L][768][256]
        int l = g / 24576, rem = g % 24576;
        int n = rem % 768, kq = rem / 768;
        const float* src = (n < 256) ? q_w : (n < 512) ? k_w : v_w;
        int nn = n & 255;
        src += (size_t)l*65536;
        size_t gidx = (size_t)l*24576 + n*32 + (kq ^ (n & 7));
        #pragma unroll
        for (int u = 0; u < 8; u++)
            qkvT[gidx*8 + u] = f2bf(src[(size_t)(kq*8+u)*256 + nn]);
    } else if ((g -= 98304) < 32768){                 // oT [L][256][256]
        int l = g >> 13, rem = g & 8191;
        int n = rem & 255, kq = rem >> 8;
        const float* src = o_w + (size_t)l*65536;
        size_t gidx = (size_t)l*8192 + n*32 + (kq ^ (n & 7));
        #pragma unroll
        for (int u = 0; u < 8; u++)
            oT[gidx*8 + u] = f2bf(src[(size_t)(kq*8+u)*256 + n]);
    } else if ((g -= 32768) < 131072){                // ff1T [L][1024][256]
        int l = g >> 15, rem = g & 32767;
        int n = rem & 1023, kq = rem >> 10;
        const float* src = ff1 + (size_t)l*262144;
        size_t gidx = (size_t)l*32768 + n*32 + (kq ^ (n & 7));
        #pragma unroll
        for (int u = 0; u < 8; u++)
            ff1T[gidx*8 + u] = f2bf(src[(size_t)(kq*8+u)*1024 + n]);
    } else if ((g -= 131072) < 131072){               // ff2T [L][256][1024]
        int l = g >> 15, rem = g & 32767;
        int n = rem & 255, kq = rem >> 8;             // kq 0..127
        const float* src = ff2 + (size_t)l*262144;
        size_t gidx = (size_t)l*32768 + n*128 + (kq & 96) + ((kq & 31) ^ (n & 7));
        #pragma unroll
        for (int u = 0; u < 8; u++)
            ff2T[gidx*8 + u] = f2bf(src[(size_t)(kq*8+u)*256 + n]);
    } else if ((g -= 131072) < 6144){                 // headT [192][256], zero-padded
        int n = g % 192, kq = g / 192;
        size_t gidx = (size_t)n*32 + (kq ^ (n & 7));
        #pragma unroll
        for (int u = 0; u < 8; u++)
            headT[gidx*8 + u] = (n < NOBJ_) ? f2bf(headw[(size_t)(kq*8+u)*NOBJ_ + n]) : (ushort)0;
    } else if ((g -= 6144) < 16384){                  // sowT [512][256]: subj|objp
        int n = g & 511, kq = g >> 9;
        const float* src = (n < 256) ? subjw : objpw;
        int nn = n & 255;
        size_t gidx = (size_t)n*32 + (kq ^ (n & 7));
        #pragma unroll
        for (int u = 0; u < 8; u++)
            sowT[gidx*8 + u] = f2bf(src[(size_t)(kq*8+u)*256 + nn]);
    } else if ((g -= 16384) < 384){                   // qkvb fp32 [L][768]
        #pragma unroll
        for (int u = 0; u < 8; u++){
            int flat = g*8 + u;
            int l = flat / 768, c = flat % 768;
            qkvb[flat] = (c < 256) ? q_b[l*256 + c] :
                         (c < 512) ? k_b[l*256 + c - 256] : v_b[l*256 + c - 512];
        }
    } else if ((g -= 384) < 64){                      // sob_b [512]
        #pragma unroll
        for (int u = 0; u < 8; u++){
            int c = g*8 + u;
            sob_b[c] = (c < 256) ? subj_b[c] : objp_b[c-256];
        }
    }
}

// ---------------- R18 tail merge 1: obj head GEMM + subj|obj GEMM ----------------
__global__ __launch_bounds__(256) void k_tail1(
        const ushort* __restrict__ hb16, const ushort* __restrict__ headT,
        const ushort* __restrict__ sowT, const float* __restrict__ obj_hb,
        const float* __restrict__ sob_b, float* __restrict__ obj_logits,
        float* __restrict__ sjhob, ushort* __restrict__ sjhob16){
    __shared__ __align__(16) char SM[40960];
    int y = blockIdx.y;
    int m0 = blockIdx.x*16;
    if (y < 3)
        dev_bgemm16<true>(SM, hb16, headT, obj_hb, nullptr, obj_logits, nullptr,
                          256, 150, 256, 256, 150, 0, m0, y*64);
    else
        dev_bgemm16<true>(SM, hb16, sowT, sob_b, nullptr, sjhob, sjhob16,
                          256, 512, 256, 256, 512, 0, m0, (y-3)*64);
}

// ---------------- R18 tail merge 2: linI GEMM + linJT GEMM + prep_obj ----------------
// linI: W=wicatT (pre-swizzled) -> PRESWZ=true. linJT: W=sjhob16 (raw) -> false.
__global__ __launch_bounds__(256) void k_tail2(
        const ushort* __restrict__ sjhob16, const ushort* __restrict__ wicatT,
        const ushort* __restrict__ wjT, const float* __restrict__ biascat,
        const float* __restrict__ sjhob,
        float* __restrict__ linI, float* __restrict__ linJT,
        ushort* __restrict__ objf){
    __shared__ __align__(16) char SM[40960];
    int bid = blockIdx.x;
    if (bid < 512){
        dev_bgemm16<true>(SM, sjhob16, wicatT, biascat, nullptr, linI, nullptr,
                          256, 512, 512, 256, 512, 0, (bid & 63)*16, (bid >> 6)*64);
    } else if (bid < 1024){
        int g = bid - 512;
        int x = g & 31, yy = (g >> 5) & 1, z = g >> 6;
        dev_bgemm16<false>(SM, wjT, sjhob16 + 256 + (size_t)z*65536, nullptr, nullptr,
                           linJT + (size_t)z*65536, nullptr,
                           256, 128, 256, 512, 128, 0, x*16, yy*64);
    } else {
        int t = (bid - 1024)*256 + threadIdx.x;     // 32768
        int ai = t & 1023, kc = (t >> 10) & 3, b = t >> 12;
        int jt = ai >> 7, ks = (ai >> 6) & 1, lane = ai & 63;
        int j = jt*16 + (lane & 15);
        int k0 = kc*64 + ks*32 + (lane >> 4)*8;
        const float* src = sjhob + (size_t)(b*128 + j)*512 + 256 + k0;
        uint o[4];
        #pragma unroll
        for (int p = 0; p < 4; p++)
            o[p] = (uint)f2bf(src[p*2]) | ((uint)f2bf(src[p*2 + 1]) << 16);
        *(uint4*)(objf + (size_t)t*8) = make_uint4(o[0], o[1], o[2], o[3]);
    }
}

// ======== k_pair: R9 version, measured-best, UNCHANGED ========
__global__ __launch_bounds__(256, 3) void k_pair(
        const float* __restrict__ sjhob, const float* __restrict__ linI,
        const float* __restrict__ linJT, const ushort* __restrict__ objf,
        const ushort* __restrict__ w3fE, const ushort* __restrict__ w3fR,
        const ushort* __restrict__ w2fR, const float* __restrict__ eh_w2,
        const float* __restrict__ eh_b2, const float* __restrict__ rh_b2,
        float* __restrict__ edge_out, float* __restrict__ rel_out){
    __shared__ __align__(16) ushort As[2048];
    __shared__ __align__(16) ushort Gs[8192];
    __shared__ __align__(16) float Rel[32*52];
    __shared__ __align__(16) float subj_sf[256];
    __shared__ __align__(16) float linEs[256];
    __shared__ __align__(16) float linRs[256];
    __shared__ __align__(16) float w2s[256];
    __shared__ __align__(16) float P[4][32];
    int tid = threadIdx.x;
    int bid = blockIdx.x;
    int jq = bid & 3, i = (bid >> 2) & 127, b = bid >> 9;
    int lane = tid & 63, w = tid >> 6;
    int l15 = lane & 15, q = lane >> 4;
    size_t rw = (size_t)(b*128 + i)*512;
    subj_sf[tid] = sjhob[rw + tid];
    linEs[tid]   = linI[rw + tid];
    linRs[tid]   = linI[rw + 256 + tid];
    w2s[tid]     = eh_w2[tid];

    uint4 po = *(const uint4*)(objf + ((size_t)(b*4)*1024 + jq*256 + tid)*8);
    f32x4 aE[4][2], aR[4][2];
    #pragma unroll
    for (int a = 0; a < 4; a++){
        aE[a][0] = (f32x4){0.f,0.f,0.f,0.f}; aE[a][1] = (f32x4){0.f,0.f,0.f,0.f};
        aR[a][0] = (f32x4){0.f,0.f,0.f,0.f}; aR[a][1] = (f32x4){0.f,0.f,0.f,0.f};
    }
    for (int kc = 0; kc < 4; kc++){
        __syncthreads();
        {
            int ks = (tid >> 6) & 1, qg = (tid >> 4) & 3;
            const float* sp = subj_sf + kc*64 + ks*32 + qg*8;
            uint oa[4] = {po.x, po.y, po.z, po.w};
            uint o[4];
            #pragma unroll
            for (int p = 0; p < 4; p++){
                float v0 = sp[p*2+0] * bf2f(oa[p]);
                float v1 = sp[p*2+1] * bf2f(oa[p] >> 16);
                o[p] = (uint)f2bf(v0) | ((uint)f2bf(v1) << 16);
            }
            *(uint4*)(As + (size_t)tid*8) = make_uint4(o[0], o[1], o[2], o[3]);
        }
        if (kc < 3)
            po = *(const uint4*)(objf + ((size_t)(b*4 + kc + 1)*1024 + jq*256 + tid)*8);
        __syncthreads();
        const ushort* wbE = w3fE + (size_t)kc*16384;
        const ushort* wbR = w3fR + (size_t)kc*16384;
        #pragma unroll
        for (int ks = 0; ks < 2; ks++){
            s16x8 bfv[2];
            bfv[0] = *(const s16x8*)(As + (size_t)((     ks)*64 + lane)*8);
            bfv[1] = *(const s16x8*)(As + (size_t)((2 +  ks)*64 + lane)*8);
            #pragma unroll
            for (int ct = 0; ct < 4; ct++){
                s16x8 afE = *(const s16x8*)(wbE + (size_t)(((w*4+ct)*2 + ks)*64 + lane)*8);
                aE[ct][0] = __builtin_amdgcn_mfma_f32_16x16x32_bf16(afE, bfv[0], aE[ct][0], 0, 0, 0);
                aE[ct][1] = __builtin_amdgcn_mfma_f32_16x16x32_bf16(afE, bfv[1], aE[ct][1], 0, 0, 0);
            }
            #pragma unroll
            for (int ct = 0; ct < 4; ct++){
                s16x8 afR = *(const s16x8*)(wbR + (size_t)(((w*4+ct)*2 + ks)*64 + lane)*8);
                aR[ct][0] = __builtin_amdgcn_mfma_f32_16x16x32_bf16(afR, bfv[0], aR[ct][0], 0, 0, 0);
                aR[ct][1] = __builtin_amdgcn_mfma_f32_16x16x32_bf16(afR, bfv[1], aR[ct][1], 0, 0, 0);
            }
        }
    }

    // ---- edge epilogue ----
    {
        float part[2] = {0.f, 0.f};
        #pragma unroll
        for (int ct = 0; ct < 4; ct++){
            int cglob = (w*4 + ct)*16 + q*4;
            float li[4] = {linEs[cglob], linEs[cglob+1], linEs[cglob+2], linEs[cglob+3]};
            float ww[4] = {w2s[cglob], w2s[cglob+1], w2s[cglob+2], w2s[cglob+3]};
            #pragma unroll
            for (int jt = 0; jt < 2; jt++){
                int jg = jq*32 + jt*16 + l15;
                const float* ljp = linJT + ((size_t)b*512 + cglob)*128 + jg;
                f32x4 v = aE[ct][jt];
                part[jt] += gelu_f(v.x + li[0] + ljp[0])   * ww[0];
                part[jt] += gelu_f(v.y + li[1] + ljp[128]) * ww[1];
                part[jt] += gelu_f(v.z + li[2] + ljp[256]) * ww[2];
                part[jt] += gelu_f(v.w + li[3] + ljp[384]) * ww[3];
            }
        }
        #pragma unroll
        for (int jt = 0; jt < 2; jt++){
            part[jt] += __shfl_xor(part[jt], 16, 64);
            part[jt] += __shfl_xor(part[jt], 32, 64);
            if (q == 0) P[w][jt*16 + l15] = part[jt];
        }
        __syncthreads();
        if (tid < 32){
            float s = eh_b2[0];
            #pragma unroll
            for (int u = 0; u < 4; u++) s += P[u][tid];
            edge_out[(size_t)(b*128 + i)*128 + jq*32 + tid] = s;
        }
    }

    // ---- rel epilogue ----
    #pragma unroll
    for (int ct = 0; ct < 4; ct++){
        int cglob = (w*4 + ct)*16 + q*4;
        float li0 = linRs[cglob],   li1 = linRs[cglob+1];
        float li2 = linRs[cglob+2], li3 = linRs[cglob+3];
        int cs = cglob >> 5, qg2 = (cglob >> 3) & 3, u0 = cglob & 7;
        #pragma unroll
        for (int jt = 0; jt < 2; jt++){
            int jg = jq*32 + jt*16 + l15;
            const float* ljp = linJT + ((size_t)b*512 + 256 + cglob)*128 + jg;
            f32x4 v = aR[ct][jt];
            ushort g0 = f2bf(gelu_f(v.x + li0 + ljp[0]));
            ushort g1 = f2bf(gelu_f(v.y + li1 + ljp[128]));
            ushort g2 = f2bf(gelu_f(v.z + li2 + ljp[256]));
            ushort g3 = f2bf(gelu_f(v.w + li3 + ljp[384]));
            uint2 pk = make_uint2((uint)g0 | ((uint)g1 << 16),
                                  (uint)g2 | ((uint)g3 << 16));
            uint off = (uint)(((jt*8 + cs)*64 + qg2*16 + l15)*16 + u0*2);
            *(uint2*)((char*)Gs + off) = pk;
        }
    }
    __syncthreads();
    f32x4 acc2[2];
    acc2[0] = (f32x4){0.f,0.f,0.f,0.f};
    acc2[1] = (f32x4){0.f,0.f,0.f,0.f};
    #pragma unroll
    for (int cs = 0; cs < 8; cs++){
        s16x8 a2 = *(const s16x8*)(w2fR + (size_t)((cs*4 + w)*64 + lane)*8);
        #pragma unroll
        for (int jt = 0; jt < 2; jt++){
            s16x8 b2 = *(const s16x8*)(Gs + (size_t)((jt*8 + cs)*64 + lane)*8);
            acc2[jt] = __builtin_amdgcn_mfma_f32_16x16x32_bf16(a2, b2, acc2[jt], 0, 0, 0);
        }
    }
    #pragma unroll
    for (int jt = 0; jt < 2; jt++){
        int jl = jt*16 + l15;
        float vv[4] = {acc2[jt].x, acc2[jt].y, acc2[jt].z, acc2[jt].w};
        #pragma unroll
        for (int rg = 0; rg < 4; rg++){
            int r = w*16 + q*4 + rg;
            if (r < 50) Rel[jl*52 + r] = vv[rg] + rh_b2[r];
        }
    }
    __syncthreads();
    size_t obase = ((size_t)(b*128 + i)*128 + jq*32)*50;
    for (int s = tid; s < 1600; s += 256){
        int j = s / 50, r = s - j*50;
        rel_out[obase + s] = Rel[j*52 + r];
    }
}

extern "C" void kernel_launch(void* const* d_in, const int* in_sizes, int n_in,
                              void* d_out, int out_size, void* d_ws, size_t ws_size,
                              hipStream_t stream){
    const int*   obj_t     = (const int*)d_in[0];
    const int*   rel_t     = (const int*)d_in[1];
    const int*   t_in      = (const int*)d_in[2];
    const float* obj_emb   = (const float*)d_in[5];
    const float* rel_emb   = (const float*)d_in[6];
    const float* time_w1   = (const float*)d_in[7];
    const float* time_b1   = (const float*)d_in[8];
    const float* time_w2   = (const float*)d_in[9];
    const float* time_b2   = (const float*)d_in[10];
    const float* ln1_g     = (const float*)d_in[11];
    const float* ln1_b     = (const float*)d_in[12];
    const float* q_w       = (const float*)d_in[13];
    const float* q_b       = (const float*)d_in[14];
    const float* k_w       = (const float*)d_in[15];
    const float* k_b       = (const float*)d_in[16];
    const float* v_w       = (const float*)d_in[17];
    const float* v_b       = (const float*)d_in[18];
    const float* o_w       = (const float*)d_in[19];
    const float* o_b       = (const float*)d_in[20];
    const float* eb_w      = (const float*)d_in[21];
    const float* eb_b      = (const float*)d_in[22];
    const float* ln2_g     = (const float*)d_in[23];
    const float* ln2_b     = (const float*)d_in[24];
    const float* ff_w1     = (const float*)d_in[25];
    const float* ff_b1     = (const float*)d_in[26];
    const float* ff_w2     = (const float*)d_in[27];
    const float* ff_b2     = (const float*)d_in[28];
    const float* obj_hw    = (const float*)d_in[29];
    const float* obj_hb    = (const float*)d_in[30];
    const float* subj_w    = (const float*)d_in[31];
    const float* subj_b    = (const float*)d_in[32];
    const float* objp_w    = (const float*)d_in[33];
    const float* objp_b    = (const float*)d_in[34];
    const float* eh_w1     = (const float*)d_in[35];
    const float* eh_b1     = (const float*)d_in[36];
    const float* eh_w2     = (const float*)d_in[37];
    const float* eh_b2     = (const float*)d_in[38];
    const float* rh_w1     = (const float*)d_in[39];
    const float* rh_b1     = (const float*)d_in[40];
    const float* rh_w2     = (const float*)d_in[41];
    const float* rh_b2     = (const float*)d_in[42];

    float* out = (float*)d_out;
    float* obj_logits  = out;                 // 8*128*150
    float* edge_logits = out + 153600;        // 8*128*128
    float* rel_logits  = out + 284672;        // 8*128*128*50

    float* w = (float*)d_ws;
    float* temb    = w;  w += 2048;
    float* hbuf    = w;  w += 262144;
    float* relb    = w;  w += 2048;
    float* linI    = w;  w += 524288;         // [1024][512]
    float* linJT   = w;  w += 524288;         // [8][512][128]
    float* biascat = w;  w += 1024;
    float* qkvb    = w;  w += 4096;
    float* sob_b   = w;  w += 512;
    float* sjhob   = w;  w += 524288;         // [1024][512] fp32 subj|obj
    ushort* us     = (ushort*)w;
    ushort* qkv16  = us;  us += 786432;       // [1024][768]
    ushort* aob16  = us;  us += 262144;
    ushort* ff1b16 = us;  us += 1048576;
    ushort* hb16   = us;  us += 262144;
    ushort* sjhob16= us;  us += 524288;       // [1024][512]
    ushort* w3fE   = us;  us += 65536;
    ushort* w3fR   = us;  us += 65536;
    ushort* w2fR   = us;  us += 16384;
    ushort* wicatT = us;  us += 131072;
    ushort* wjT    = us;  us += 131072;
    ushort* objf   = us;  us += 262144;
    ushort* qkvT   = us;  us += 786432;
    ushort* oT     = us;  us += 262144;
    ushort* ff1T   = us;  us += 1048576;
    ushort* ff2T   = us;  us += 1048576;
    ushort* headT  = us;  us += 49152;
    ushort* sowT   = us;  us += 131072;       // [512][256] subj|objp

    k_prep_w<<<215, 256, 0, stream>>>(eh_w1, rh_w1, rh_w2, eh_b1, rh_b1,
                                      rel_emb, eb_w, eb_b,
                                      t_in, time_w1, time_b1, time_w2, time_b2,
                                      w3fE, w3fR, wjT, w2fR, wicatT, biascat,
                                      relb, temb);
    k_prep_bw<<<2650, 256, 0, stream>>>(q_w, k_w, v_w, o_w, ff_w1, ff_w2,
                                        obj_hw, subj_w, objp_w, q_b, k_b, v_b,
                                        subj_b, objp_b,
                                        obj_t, obj_emb, temb, hbuf,
                                        qkvT, oT, ff1T, ff2T, headT, sowT, qkvb, sob_b);

    for (int l = 0; l < LL; l++){
        k_lngemm<<<dim3(32,12), 256, 0, stream>>>(hbuf, ln1_g + l*DD, ln1_b + l*DD,
                qkvT + (size_t)l*196608, qkvb + l*768, qkv16, 768, 0);
        k_attn<<<256, 256, 0, stream>>>(qkv16, rel_t, relb + l*NREL_*HH, aob16);
        k_bgemm16<<<dim3(64,4), 256, 0, stream>>>(aob16, oT + (size_t)l*65536,
                o_b + l*DD, hbuf, hbuf, nullptr, 256, 256, 256, 256, 256, 0);
        k_lngemm<<<dim3(32,16), 256, 0, stream>>>(hbuf, ln2_g + l*DD, ln2_b + l*DD,
                ff1T + (size_t)l*262144, ff_b1 + l*FFD, ff1b16, 1024, 1);
        k_bgemm16<<<dim3(64,4), 256, 0, stream>>>(ff1b16, ff2T + (size_t)l*262144,
                ff_b2 + l*DD, hbuf, hbuf, hb16, 1024, 256, 1024, 1024, 256, 0);
    }

    // tail: head+sow merged; linI+linJT+prep_obj merged
    k_tail1<<<dim3(64,11), 256, 0, stream>>>(hb16, headT, sowT, obj_hb, sob_b,
                                             obj_logits, sjhob, sjhob16);
    k_tail2<<<1152, 256, 0, stream>>>(sjhob16, wicatT, wjT, biascat, sjhob,
                                      linI, linJT, objf);

    k_pair<<<4096, 256, 0, stream>>>(sjhob, linI, linJT, objf, w3fE, w3fR,
                                     w2fR, eh_w2, eh_b2, rh_b2,
                                     edge_logits, rel_logits);
}

// Round 14
// 429.882 us; speedup vs baseline: 1.0148x; 1.0148x over previous
//
#include <hip/hip_runtime.h>
#include <hip/hip_bf16.h>
#include <math.h>

#define BB 8
#define NN 128
#define DD 256
#define HH 8
#define LL 4
#define FFD 1024
#define HD 32
#define NOBJ_ 150
#define NREL_ 51

typedef __attribute__((ext_vector_type(4))) float f32x4;
typedef __attribute__((ext_vector_type(8))) short s16x8;

__device__ __forceinline__ float erf_f(float x){
    float ax = fabsf(x);
    float t = __builtin_amdgcn_rcpf(1.f + 0.3275911f*ax);
    float y = t*(0.254829592f + t*(-0.284496736f + t*(1.421413741f +
              t*(-1.453152027f + t*1.061405429f))));
    float r = 1.f - y*__expf(-ax*ax);
    return copysignf(r, x);
}
__device__ __forceinline__ float gelu_f(float x){
    return 0.5f * x * (1.0f + erf_f(x * 0.70710678118654752f));
}
__device__ __forceinline__ ushort f2bf(float f){
    uint u = __float_as_uint(f);
    u += 0x7fff + ((u >> 16) & 1);
    return (ushort)(u >> 16);
}
__device__ __forceinline__ float bf2f(uint u){
    return __uint_as_float((u & 0xffffu) << 16);
}

// ---------------- fused LN + bf16 MFMA GEMM (M-tile 32, K=256 fixed) ----------------
__global__ __launch_bounds__(256) void k_lngemm(
        const float* __restrict__ A, const float* __restrict__ gw,
        const float* __restrict__ bw, const ushort* __restrict__ WT,
        const float* __restrict__ bias, ushort* __restrict__ Cb,
        int Nc, int act){
    __shared__ __align__(16) ushort As[8192];    // 32 x 256 bf16, xor-swizzled
    __shared__ __align__(16) ushort Ws[16384];   // 64 x 256 bf16, xor-swizzled
    int tid = threadIdx.x;
    int m0 = blockIdx.x*32, n0 = blockIdx.y*64;
    int r = tid >> 3, p = tid & 7;
    const float* ap = A + (size_t)(m0 + r)*256 + p*32;
    float x[32];
    float s1 = 0.f, s2 = 0.f;
    #pragma unroll
    for (int e4 = 0; e4 < 8; e4++){
        float4 v = *(const float4*)(ap + e4*4);
        x[e4*4+0]=v.x; x[e4*4+1]=v.y; x[e4*4+2]=v.z; x[e4*4+3]=v.w;
        s1 += v.x+v.y+v.z+v.w;
        s2 += v.x*v.x+v.y*v.y+v.z*v.z+v.w*v.w;
    }
    #pragma unroll
    for (int d = 1; d < 8; d <<= 1){
        s1 += __shfl_xor(s1, d, 64);
        s2 += __shfl_xor(s2, d, 64);
    }
    float mean = s1*(1.f/256.f);
    float var = s2*(1.f/256.f) - mean*mean;
    float rstd = rsqrtf(var + 1e-5f);
    #pragma unroll
    for (int j = 0; j < 4; j++){
        int kq = p*4 + j;
        uint o[4];
        #pragma unroll
        for (int pp = 0; pp < 4; pp++){
            int e = j*8 + pp*2;
            int k = p*32 + e;
            float v0 = (x[e]   - mean)*rstd*gw[k]   + bw[k];
            float v1 = (x[e+1] - mean)*rstd*gw[k+1] + bw[k+1];
            o[pp] = (uint)f2bf(v0) | ((uint)f2bf(v1) << 16);
        }
        int phys = r*32 + (kq ^ (r & 7));
        *(uint4*)(As + (size_t)phys*8) = make_uint4(o[0], o[1], o[2], o[3]);
    }
    #pragma unroll
    for (int rr = 0; rr < 8; rr++){
        int gi = tid + rr*256;
        int n = gi >> 5, kq = gi & 31;
        uint4 v = *(const uint4*)(WT + (size_t)(n0+n)*256 + kq*8);
        *(uint4*)(Ws + (size_t)(n*32 + (kq ^ (n&7)))*8) = v;
    }
    __syncthreads();
    int lane = tid & 63, w = tid >> 6, l15 = lane & 15, q = lane >> 4;
    f32x4 acc[2];
    acc[0] = (f32x4){0.f,0.f,0.f,0.f};
    acc[1] = (f32x4){0.f,0.f,0.f,0.f};
    int m = (w&1)*16 + l15;
    #pragma unroll
    for (int k0 = 0; k0 < 8; k0++){
        int kq = k0*4 + q;
        s16x8 af = *(const s16x8*)(As + (size_t)(m*32 + (kq ^ (m&7)))*8);
        #pragma unroll
        for (int t = 0; t < 2; t++){
            int n = ((w>>1)*2 + t)*16 + l15;
            s16x8 bf = *(const s16x8*)(Ws + (size_t)(n*32 + (kq ^ (n&7)))*8);
            acc[t] = __builtin_amdgcn_mfma_f32_16x16x32_bf16(af, bf, acc[t], 0, 0, 0);
        }
    }
    int mb = (w&1)*16;
    #pragma unroll
    for (int t = 0; t < 2; t++){
        int n = n0 + ((w>>1)*2 + t)*16 + l15;
        if (n < Nc){
            float bv = bias ? bias[n] : 0.f;
            float vv[4] = {acc[t].x, acc[t].y, acc[t].z, acc[t].w};
            #pragma unroll
            for (int rr = 0; rr < 4; rr++){
                int m2 = m0 + mb + q*4 + rr;
                float v = vv[rr] + bv;
                if (act) v = gelu_f(v);
                Cb[(size_t)m2*Nc + n] = f2bf(v);
            }
        }
    }
}

// ---------------- BM=16 GEMM tile as device fn (verified bit-correct via R17 run) ----------------
__device__ __forceinline__ void dev_bgemm16(char* SMEM,
        const ushort* __restrict__ A, const ushort* __restrict__ WT,
        const float* __restrict__ bias, const float* __restrict__ R,
        float* __restrict__ C, ushort* __restrict__ Cb,
        int K, int Nc, int lda, int ldw, int ldc, int act, int m0, int n0){
    ushort* As = (ushort*)SMEM;           // 16x256 = 8 KB
    ushort* Ws = (ushort*)(SMEM + 8192);  // 64x256 = 32 KB
    int tid = threadIdx.x;
    int lane = tid & 63, w = tid >> 6;
    int l15 = lane & 15, q = lane >> 4;
    f32x4 acc = (f32x4){0.f,0.f,0.f,0.f};
    int m = l15;

    for (int kb = 0; kb < K; kb += 256){
        if (kb) __syncthreads();
        #pragma unroll
        for (int rr = 0; rr < 2; rr++){
            int gi = tid + rr*256;
            int mm = gi >> 5, kq = gi & 31;
            uint4 v = *(const uint4*)(A + (size_t)(m0+mm)*lda + kb + kq*8);
            *(uint4*)(As + (size_t)(mm*32 + (kq ^ (mm&7)))*8) = v;
        }
        #pragma unroll
        for (int rr = 0; rr < 8; rr++){
            int gi = tid + rr*256;
            int n = gi >> 5, kq = gi & 31;
            uint4 v = *(const uint4*)(WT + (size_t)(n0+n)*ldw + kb + kq*8);
            *(uint4*)(Ws + (size_t)(n*32 + (kq ^ (n&7)))*8) = v;
        }
        __syncthreads();
        #pragma unroll
        for (int k0 = 0; k0 < 8; k0++){
            int kq = k0*4 + q;
            s16x8 af = *(const s16x8*)(As + (size_t)(m*32 + (kq ^ (m&7)))*8);
            int n = w*16 + l15;
            s16x8 bf = *(const s16x8*)(Ws + (size_t)(n*32 + (kq ^ (n&7)))*8);
            acc = __builtin_amdgcn_mfma_f32_16x16x32_bf16(af, bf, acc, 0, 0, 0);
        }
    }
    {
        int n = n0 + w*16 + l15;
        if (n < Nc){
            float bv = bias ? bias[n] : 0.f;
            float vv[4] = {acc.x, acc.y, acc.z, acc.w};
            #pragma unroll
            for (int r = 0; r < 4; r++){
                int m2 = m0 + q*4 + r;
                float v = vv[r] + bv;
                if (act) v = gelu_f(v);
                size_t off = (size_t)m2*ldc + n;
                if (R) v += R[off];
                if (C) C[off] = v;
                if (Cb) Cb[off] = f2bf(v);
            }
        }
    }
}

// ---------------- generic bf16 MFMA GEMM (standalone, layer loop) ----------------
template<int BM>
__global__ __launch_bounds__(256) void k_bgemm(
        const ushort* __restrict__ A, const ushort* __restrict__ WT,
        const float* __restrict__ bias, const float* __restrict__ R,
        float* __restrict__ C, ushort* __restrict__ Cb,
        int K, int Nc, int lda, int ldw, int ldc, int act,
        long bsA, long bsW, long bsC, long bsB){
    __shared__ __align__(16) ushort As[BM*256];
    __shared__ __align__(16) ushort Ws[16384];
    int tid = threadIdx.x;
    int z = blockIdx.z;
    const ushort* Ab = A + (size_t)z*bsA;
    const ushort* Wb = WT + (size_t)z*bsW;
    const float* bz = bias ? bias + (size_t)z*bsB : nullptr;
    int m0 = blockIdx.x*BM, n0 = blockIdx.y*64;
    int lane = tid & 63, w = tid >> 6;
    int l15 = lane & 15, q = lane >> 4;
    constexpr int NACC = (BM == 32) ? 2 : 1;
    f32x4 acc[NACC];
    #pragma unroll
    for (int i = 0; i < NACC; i++) acc[i] = (f32x4){0.f,0.f,0.f,0.f};
    int m = (BM == 32) ? (w&1)*16 + l15 : l15;

    for (int kb = 0; kb < K; kb += 256){
        if (kb) __syncthreads();
        #pragma unroll
        for (int rr = 0; rr < BM/8; rr++){
            int gi = tid + rr*256;
            int mm = gi >> 5, kq = gi & 31;
            uint4 v = *(const uint4*)(Ab + (size_t)(m0+mm)*lda + kb + kq*8);
            *(uint4*)(As + (size_t)(mm*32 + (kq ^ (mm&7)))*8) = v;
        }
        #pragma unroll
        for (int rr = 0; rr < 8; rr++){
            int gi = tid + rr*256;
            int n = gi >> 5, kq = gi & 31;
            uint4 v = *(const uint4*)(Wb + (size_t)(n0+n)*ldw + kb + kq*8);
            *(uint4*)(Ws + (size_t)(n*32 + (kq ^ (n&7)))*8) = v;
        }
        __syncthreads();
        #pragma unroll
        for (int k0 = 0; k0 < 8; k0++){
            int kq = k0*4 + q;
            s16x8 af = *(const s16x8*)(As + (size_t)(m*32 + (kq ^ (m&7)))*8);
            if (BM == 32){
                #pragma unroll
                for (int t = 0; t < NACC; t++){
                    int n = ((w>>1)*2 + t)*16 + l15;
                    s16x8 bf = *(const s16x8*)(Ws + (size_t)(n*32 + (kq ^ (n&7)))*8);
                    acc[t] = __builtin_amdgcn_mfma_f32_16x16x32_bf16(af, bf, acc[t], 0, 0, 0);
                }
            } else {
                int n = w*16 + l15;
                s16x8 bf = *(const s16x8*)(Ws + (size_t)(n*32 + (kq ^ (n&7)))*8);
                acc[0] = __builtin_amdgcn_mfma_f32_16x16x32_bf16(af, bf, acc[0], 0, 0, 0);
            }
        }
    }
    int mb = (BM == 32) ? (w&1)*16 : 0;
    #pragma unroll
    for (int ti = 0; ti < NACC; ti++){
        int n = (BM == 32) ? n0 + ((w>>1)*2 + ti)*16 + l15 : n0 + w*16 + l15;
        if (n < Nc){
            float bv = bz ? bz[n] : 0.f;
            float vv[4] = {acc[ti].x, acc[ti].y, acc[ti].z, acc[ti].w};
            #pragma unroll
            for (int r = 0; r < 4; r++){
                int m2 = m0 + mb + q*4 + r;
                float v = vv[r] + bv;
                if (act) v = gelu_f(v);
                size_t off = (size_t)z*bsC + (size_t)m2*ldc + n;
                if (R) v += R[off];
                if (C) C[off] = v;
                if (Cb) Cb[off] = f2bf(v);
            }
        }
    }
}

// ---------------- attention (bf16 qkv in, bf16 out) — R15 LDS-halved ----------------
__global__ __launch_bounds__(256) void k_attn(const ushort* __restrict__ qkv,
        const int* __restrict__ rel_t, const float* __restrict__ relb,
        ushort* __restrict__ out){
    __shared__ float qs[32][33];
    __shared__ float ks[128][33];
    __shared__ float vs[128][36];
    __shared__ float S[32][129];
    __shared__ float red[32][8];
    __shared__ float rowmax[32], rowinv[32];
    int bid = blockIdx.x;
    int it = bid & 3, h = (bid >> 2) & 7, b = bid >> 5;
    int tid = threadIdx.x;
    int i0 = it*32;
    const float scale = 0.17677669529663687f;
    #pragma unroll
    for (int qq = 0; qq < 4; qq++){
        int e = tid + qq*256; int i = e >> 5, d = e & 31;
        qs[i][d] = bf2f(qkv[(size_t)(b*NN + i0 + i)*768 + h*HD + d]);
    }
    #pragma unroll
    for (int qq = 0; qq < 16; qq++){
        int e = tid + qq*256; int j = e >> 5, d = e & 31;
        ks[j][d] = bf2f(qkv[(size_t)(b*NN + j)*768 + 256 + h*HD + d]);
        vs[j][d] = bf2f(qkv[(size_t)(b*NN + j)*768 + 512 + h*HD + d]);
    }
    __syncthreads();
    int i = tid >> 3, s = tid & 7;
    {
        float qreg[32];
        #pragma unroll
        for (int kk = 0; kk < 32; kk++) qreg[kk] = qs[i][kk];
        for (int j = s; j < 128; j += 8){
            float acc = 0.f;
            #pragma unroll
            for (int kk = 0; kk < 32; kk++) acc += qreg[kk] * ks[j][kk];
            int r = rel_t[(size_t)(b*NN + i0 + i)*NN + j];
            S[i][j] = acc * scale + relb[r*HH + h];
        }
    }
    __syncthreads();
    float lm = -1e30f;
    for (int j = s; j < 128; j += 8) lm = fmaxf(lm, S[i][j]);
    red[i][s] = lm; __syncthreads();
    if (s == 0){
        float m = red[i][0];
        #pragma unroll
        for (int u = 1; u < 8; u++) m = fmaxf(m, red[i][u]);
        rowmax[i] = m;
    }
    __syncthreads();
    float rm = rowmax[i];
    float ls = 0.f;
    for (int j = s; j < 128; j += 8){ float e = __expf(S[i][j] - rm); S[i][j] = e; ls += e; }
    red[i][s] = ls; __syncthreads();
    if (s == 0){
        float sum = 0.f;
        #pragma unroll
        for (int u = 0; u < 8; u++) sum += red[i][u];
        rowinv[i] = 1.f / sum;
    }
    __syncthreads();
    {
        int d0 = s*4;
        float a0 = 0.f, a1 = 0.f, a2 = 0.f, a3 = 0.f;
        for (int j = 0; j < 128; j++){
            float p = S[i][j];
            float4 v4 = *(const float4*)&vs[j][d0];
            a0 += p*v4.x; a1 += p*v4.y; a2 += p*v4.z; a3 += p*v4.w;
        }
        float rinv = rowinv[i];
        size_t ob = (size_t)(b*NN + i0 + i)*DD + h*HD + d0;
        out[ob+0] = f2bf(a0 * rinv);
        out[ob+1] = f2bf(a1 * rinv);
        out[ob+2] = f2bf(a2 * rinv);
        out[ob+3] = f2bf(a3 * rinv);
    }
}

// ---------------- prep: pair-head weights + relbias + biascat + time MLP ----------------
__global__ __launch_bounds__(256) void k_prep_w(const float* __restrict__ eh1,
        const float* __restrict__ rh1, const float* __restrict__ rh_w2,
        const float* __restrict__ eh_b1, const float* __restrict__ rh_b1,
        const float* __restrict__ rel_emb, const float* __restrict__ eb_w,
        const float* __restrict__ eb_b,
        const int* __restrict__ t, const float* __restrict__ tw1,
        const float* __restrict__ tb1, const float* __restrict__ tw2,
        const float* __restrict__ tb2,
        ushort* __restrict__ w3fE, ushort* __restrict__ w3fR,
        ushort* __restrict__ wjT, ushort* __restrict__ w2fR,
        ushort* __restrict__ wicatT, float* __restrict__ biascat,
        float* __restrict__ relb, float* __restrict__ temb){
    __shared__ float t0[DD];
    __shared__ float y1[DD];
    if (blockIdx.x >= 207){                       // ---- time MLP blocks ----
        int b = blockIdx.x - 207, d = threadIdx.x;
        float tv = (float)t[b];
        float v;
        if (d < 128){
            float fr = expf(-9.210340371976184f * (float)d / 128.f);
            v = cosf(tv * fr);
        } else {
            float fr = expf(-9.210340371976184f * (float)(d - 128) / 128.f);
            v = sinf(tv * fr);
        }
        t0[d] = v; __syncthreads();
        float acc = tb1[d];
        for (int k = 0; k < DD; k++) acc += t0[k] * tw1[k*DD + d];
        acc = acc / (1.f + expf(-acc));
        y1[d] = acc; __syncthreads();
        float acc2 = tb2[d];
        for (int k = 0; k < DD; k++) acc2 += y1[k] * tw2[k*DD + d];
        temb[b*DD + d] = acc2;
        return;
    }
    int idx = blockIdx.x*256 + threadIdx.x;
    if (idx < 16384){
        int head = idx >> 13;                    // 0=E, 1=R
        int g = idx & 8191;
        int kc = g >> 11, rem = g & 2047;
        int CT = rem >> 7, ks = (rem >> 6) & 1, lane = rem & 63;
        int c = CT*16 + (lane & 15);
        const float* src = head ? rh1 : eh1;
        ushort* dst = head ? w3fR : w3fE;
        #pragma unroll
        for (int u = 0; u < 8; u++){
            int k = kc*64 + ks*32 + (lane >> 4)*8 + u;
            dst[(size_t)g*8 + u] = f2bf(src[(size_t)(768+k)*256 + c]);
        }
    } else if (idx < 32768){
        int g = idx - 16384;                     // wjT, coalesced-read remap
        int c = g & 511, kq = g >> 9;            // kq 0..31
        size_t gidx = (size_t)c*32 + kq;
        #pragma unroll
        for (int u = 0; u < 8; u++){
            int k = kq*8 + u;
            float v = (c < 256) ? eh1[(size_t)(256+k)*256 + c] - eh1[(size_t)(512+k)*256 + c]
                                : rh1[(size_t)(256+k)*256 + (c-256)] - rh1[(size_t)(512+k)*256 + (c-256)];
            wjT[gidx*8 + u] = f2bf(v);
        }
    } else if (idx < 34816){
        int gg = idx - 32768;                    // w2fR 2048 granules
        int lane = gg & 63, rt = (gg >> 6) & 3, cs = (gg >> 8) & 3, g2 = gg >> 10;
        int r = rt*16 + (lane & 15);
        #pragma unroll
        for (int u = 0; u < 8; u++){
            int c = g2*128 + cs*32 + (lane >> 4)*8 + u;
            w2fR[(size_t)gg*8 + u] = (r < 50) ? f2bf(rh_w2[(size_t)c*50 + r]) : (ushort)0;
        }
    } else if (idx < 51200){
        int g = idx - 34816;                     // wicatT, coalesced-read remap
        int c = g & 511, kq = g >> 9;
        size_t gidx = (size_t)c*32 + kq;
        #pragma unroll
        for (int u = 0; u < 8; u++){
            int k = kq*8 + u;
            float v = (c < 256) ? eh1[(size_t)k*256 + c] + eh1[(size_t)(512+k)*256 + c]
                                : rh1[(size_t)k*256 + (c-256)] + rh1[(size_t)(512+k)*256 + (c-256)];
            wicatT[gidx*8 + u] = f2bf(v);
        }
    } else if (idx < 51328){
        int bg = idx - 51200;                    // biascat2 [1024]: eh_b1|rh_b1|0|0
        #pragma unroll
        for (int u = 0; u < 8; u++){
            int c = bg*8 + u;
            biascat[c] = (c < 256) ? eh_b1[c] : (c < 512) ? rh_b1[c-256] : 0.f;
        }
    } else if (idx < 52960){
        int t2 = idx - 51328;                    // relbias 4*51*8
        int l = t2 / (NREL_*HH);
        int rem = t2 - l*(NREL_*HH);
        int r = rem >> 3, h = rem & 7;
        float acc = eb_b[l*HH + h];
        for (int d = 0; d < DD; d++) acc += rel_emb[r*DD + d] * eb_w[(size_t)l*DD*HH + d*HH + h];
        relb[t2] = acc;
    }
}

// ---------------- prep: trunk/head weights -> transposed bf16 + bias concats ----------------
__global__ __launch_bounds__(256) void k_prep_bw(
        const float* __restrict__ q_w, const float* __restrict__ k_w,
        const float* __restrict__ v_w, const float* __restrict__ o_w,
        const float* __restrict__ ff1, const float* __restrict__ ff2,
        const float* __restrict__ headw, const float* __restrict__ subjw,
        const float* __restrict__ objpw,
        const float* __restrict__ q_b, const float* __restrict__ k_b,
        const float* __restrict__ v_b,
        const float* __restrict__ subj_b, const float* __restrict__ objp_b,
        const int* __restrict__ obj_t, const float* __restrict__ obj_emb,
        const float* __restrict__ temb, float* __restrict__ hbuf,
        ushort* __restrict__ qkvT, ushort* __restrict__ oT,
        ushort* __restrict__ ff1T, ushort* __restrict__ ff2T,
        ushort* __restrict__ headT, ushort* __restrict__ sowT,
        float* __restrict__ qkvb, float* __restrict__ sob_b){
    if (blockIdx.x >= 1626){                     // ---- h init ----
        int idx = (blockIdx.x - 1626)*256 + threadIdx.x;
        int d = idx & 255, n = (idx >> 8) & 127, b = idx >> 15;
        int o = obj_t[b*NN + n];
        hbuf[idx] = obj_emb[o*DD + d] + temb[b*DD + d];
        return;
    }
    int g = blockIdx.x*256 + threadIdx.x;
    if (g < 98304){                                   // qkvT [L][768][256]
        int l = g / 24576, rem = g % 24576;
        int n = rem % 768, kq = rem / 768;
        const float* src = (n < 256) ? q_w : (n < 512) ? k_w : v_w;
        int nn = n & 255;
        src += (size_t)l*65536;
        size_t gidx = (size_t)l*24576 + n*32 + kq;
        #pragma unroll
        for (int u = 0; u < 8; u++)
            qkvT[gidx*8 + u] = f2bf(src[(size_t)(kq*8+u)*256 + nn]);
    } else if ((g -= 98304) < 32768){                 // oT [L][256][256]
        int l = g >> 13, rem = g & 8191;
        int n = rem & 255, kq = rem >> 8;
        const float* src = o_w + (size_t)l*65536;
        size_t gidx = (size_t)l*8192 + n*32 + kq;
        #pragma unroll
        for (int u = 0; u < 8; u++)
            oT[gidx*8 + u] = f2bf(src[(size_t)(kq*8+u)*256 + n]);
    } else if ((g -= 32768) < 131072){                // ff1T [L][1024][256]
        int l = g >> 15, rem = g & 32767;
        int n = rem & 1023, kq = rem >> 10;
        const float* src = ff1 + (size_t)l*262144;
        size_t gidx = (size_t)l*32768 + n*32 + kq;
        #pragma unroll
        for (int u = 0; u < 8; u++)
            ff1T[gidx*8 + u] = f2bf(src[(size_t)(kq*8+u)*1024 + n]);
    } else if ((g -= 131072) < 131072){               // ff2T [L][256][1024]
        int l = g >> 15, rem = g & 32767;
        int n = rem & 255, kq = rem >> 8;             // kq 0..127
        const float* src = ff2 + (size_t)l*262144;
        size_t gidx = (size_t)l*32768 + n*128 + kq;
        #pragma unroll
        for (int u = 0; u < 8; u++)
            ff2T[gidx*8 + u] = f2bf(src[(size_t)(kq*8+u)*256 + n]);
    } else if ((g -= 131072) < 6144){                 // headT [192][256], zero-padded
        int n = g % 192, kq = g / 192;
        size_t gidx = (size_t)n*32 + kq;
        #pragma unroll
        for (int u = 0; u < 8; u++)
            headT[gidx*8 + u] = (n < NOBJ_) ? f2bf(headw[(size_t)(kq*8+u)*NOBJ_ + n]) : (ushort)0;
    } else if ((g -= 6144) < 16384){                  // sowT [512][256]: subj|objp
        int n = g & 511, kq = g >> 9;
        const float* src = (n < 256) ? subjw : objpw;
        int nn = n & 255;
        size_t gidx = (size_t)n*32 + kq;
        #pragma unroll
        for (int u = 0; u < 8; u++)
            sowT[gidx*8 + u] = f2bf(src[(size_t)(kq*8+u)*256 + nn]);
    } else if ((g -= 16384) < 384){                   // qkvb fp32 [L][768]
        #pragma unroll
        for (int u = 0; u < 8; u++){
            int flat = g*8 + u;
            int l = flat / 768, c = flat % 768;
            qkvb[flat] = (c < 256) ? q_b[l*256 + c] :
                         (c < 512) ? k_b[l*256 + c - 256] : v_b[l*256 + c - 512];
        }
    } else if ((g -= 384) < 64){                      // sob_b [512]
        #pragma unroll
        for (int u = 0; u < 8; u++){
            int c = g*8 + u;
            sob_b[c] = (c < 256) ? subj_b[c] : objp_b[c-256];
        }
    }
}

// ---------------- R18 tail merge 1: obj head GEMM + subj|obj GEMM ----------------
__global__ __launch_bounds__(256) void k_tail1(
        const ushort* __restrict__ hb16, const ushort* __restrict__ headT,
        const ushort* __restrict__ sowT, const float* __restrict__ obj_hb,
        const float* __restrict__ sob_b, float* __restrict__ obj_logits,
        float* __restrict__ sjhob, ushort* __restrict__ sjhob16){
    __shared__ __align__(16) char SM[40960];
    int y = blockIdx.y;
    int m0 = blockIdx.x*16;
    if (y < 3)
        dev_bgemm16(SM, hb16, headT, obj_hb, nullptr, obj_logits, nullptr,
                    256, 150, 256, 256, 150, 0, m0, y*64);
    else
        dev_bgemm16(SM, hb16, sowT, sob_b, nullptr, sjhob, sjhob16,
                    256, 512, 256, 256, 512, 0, m0, (y-3)*64);
}

// ---------------- R18 tail merge 2: linI GEMM + linJT GEMM + prep_obj ----------------
__global__ __launch_bounds__(256) void k_tail2(
        const ushort* __restrict__ sjhob16, const ushort* __restrict__ wicatT,
        const ushort* __restrict__ wjT, const float* __restrict__ biascat,
        const float* __restrict__ sjhob,
        float* __restrict__ linI, float* __restrict__ linJT,
        ushort* __restrict__ objf){
    __shared__ __align__(16) char SM[40960];
    int bid = blockIdx.x;
    if (bid < 512){
        dev_bgemm16(SM, sjhob16, wicatT, biascat, nullptr, linI, nullptr,
                    256, 512, 512, 256, 512, 0, (bid & 63)*16, (bid >> 6)*64);
    } else if (bid < 1024){
        int g = bid - 512;
        int x = g & 31, yy = (g >> 5) & 1, z = g >> 6;
        dev_bgemm16(SM, wjT, sjhob16 + 256 + (size_t)z*65536, nullptr, nullptr,
                    linJT + (size_t)z*65536, nullptr,
                    256, 128, 256, 512, 128, 0, x*16, yy*64);
    } else {
        int t = (bid - 1024)*256 + threadIdx.x;     // 32768
        int ai = t & 1023, kc = (t >> 10) & 3, b = t >> 12;
        int jt = ai >> 7, ks = (ai >> 6) & 1, lane = ai & 63;
        int j = jt*16 + (lane & 15);
        int k0 = kc*64 + ks*32 + (lane >> 4)*8;
        const float* src = sjhob + (size_t)(b*128 + j)*512 + 256 + k0;
        uint o[4];
        #pragma unroll
        for (int p = 0; p < 4; p++)
            o[p] = (uint)f2bf(src[p*2]) | ((uint)f2bf(src[p*2 + 1]) << 16);
        *(uint4*)(objf + (size_t)t*8) = make_uint4(o[0], o[1], o[2], o[3]);
    }
}

// ======== k_pair: R9 version, measured-best, UNCHANGED ========
__global__ __launch_bounds__(256, 3) void k_pair(
        const float* __restrict__ sjhob, const float* __restrict__ linI,
        const float* __restrict__ linJT, const ushort* __restrict__ objf,
        const ushort* __restrict__ w3fE, const ushort* __restrict__ w3fR,
        const ushort* __restrict__ w2fR, const float* __restrict__ eh_w2,
        const float* __restrict__ eh_b2, const float* __restrict__ rh_b2,
        float* __restrict__ edge_out, float* __restrict__ rel_out){
    __shared__ __align__(16) ushort As[2048];
    __shared__ __align__(16) ushort Gs[8192];
    __shared__ __align__(16) float Rel[32*52];
    __shared__ __align__(16) float subj_sf[256];
    __shared__ __align__(16) float linEs[256];
    __shared__ __align__(16) float linRs[256];
    __shared__ __align__(16) float w2s[256];
    __shared__ __align__(16) float P[4][32];
    int tid = threadIdx.x;
    int bid = blockIdx.x;
    int jq = bid & 3, i = (bid >> 2) & 127, b = bid >> 9;
    int lane = tid & 63, w = tid >> 6;
    int l15 = lane & 15, q = lane >> 4;
    size_t rw = (size_t)(b*128 + i)*512;
    subj_sf[tid] = sjhob[rw + tid];
    linEs[tid]   = linI[rw + tid];
    linRs[tid]   = linI[rw + 256 + tid];
    w2s[tid]     = eh_w2[tid];

    uint4 po = *(const uint4*)(objf + ((size_t)(b*4)*1024 + jq*256 + tid)*8);
    f32x4 aE[4][2], aR[4][2];
    #pragma unroll
    for (int a = 0; a < 4; a++){
        aE[a][0] = (f32x4){0.f,0.f,0.f,0.f}; aE[a][1] = (f32x4){0.f,0.f,0.f,0.f};
        aR[a][0] = (f32x4){0.f,0.f,0.f,0.f}; aR[a][1] = (f32x4){0.f,0.f,0.f,0.f};
    }
    for (int kc = 0; kc < 4; kc++){
        __syncthreads();
        {
            int ks = (tid >> 6) & 1, qg = (tid >> 4) & 3;
            const float* sp = subj_sf + kc*64 + ks*32 + qg*8;
            uint oa[4] = {po.x, po.y, po.z, po.w};
            uint o[4];
            #pragma unroll
            for (int p = 0; p < 4; p++){
                float v0 = sp[p*2+0] * bf2f(oa[p]);
                float v1 = sp[p*2+1] * bf2f(oa[p] >> 16);
                o[p] = (uint)f2bf(v0) | ((uint)f2bf(v1) << 16);
            }
            *(uint4*)(As + (size_t)tid*8) = make_uint4(o[0], o[1], o[2], o[3]);
        }
        if (kc < 3)
            po = *(const uint4*)(objf + ((size_t)(b*4 + kc + 1)*1024 + jq*256 + tid)*8);
        __syncthreads();
        const ushort* wbE = w3fE + (size_t)kc*16384;
        const ushort* wbR = w3fR + (size_t)kc*16384;
        #pragma unroll
        for (int ks = 0; ks < 2; ks++){
            s16x8 bfv[2];
            bfv[0] = *(const s16x8*)(As + (size_t)((     ks)*64 + lane)*8);
            bfv[1] = *(const s16x8*)(As + (size_t)((2 +  ks)*64 + lane)*8);
            #pragma unroll
            for (int ct = 0; ct < 4; ct++){
                s16x8 afE = *(const s16x8*)(wbE + (size_t)(((w*4+ct)*2 + ks)*64 + lane)*8);
                aE[ct][0] = __builtin_amdgcn_mfma_f32_16x16x32_bf16(afE, bfv[0], aE[ct][0], 0, 0, 0);
                aE[ct][1] = __builtin_amdgcn_mfma_f32_16x16x32_bf16(afE, bfv[1], aE[ct][1], 0, 0, 0);
            }
            #pragma unroll
            for (int ct = 0; ct < 4; ct++){
                s16x8 afR = *(const s16x8*)(wbR + (size_t)(((w*4+ct)*2 + ks)*64 + lane)*8);
                aR[ct][0] = __builtin_amdgcn_mfma_f32_16x16x32_bf16(afR, bfv[0], aR[ct][0], 0, 0, 0);
                aR[ct][1] = __builtin_amdgcn_mfma_f32_16x16x32_bf16(afR, bfv[1], aR[ct][1], 0, 0, 0);
            }
        }
    }

    // ---- edge epilogue ----
    {
        float part[2] = {0.f, 0.f};
        #pragma unroll
        for (int ct = 0; ct < 4; ct++){
            int cglob = (w*4 + ct)*16 + q*4;
            float li[4] = {linEs[cglob], linEs[cglob+1], linEs[cglob+2], linEs[cglob+3]};
            float ww[4] = {w2s[cglob], w2s[cglob+1], w2s[cglob+2], w2s[cglob+3]};
            #pragma unroll
            for (int jt = 0; jt < 2; jt++){
                int jg = jq*32 + jt*16 + l15;
                const float* ljp = linJT + ((size_t)b*512 + cglob)*128 + jg;
                f32x4 v = aE[ct][jt];
                part[jt] += gelu_f(v.x + li[0] + ljp[0])   * ww[0];
                part[jt] += gelu_f(v.y + li[1] + ljp[128]) * ww[1];
                part[jt] += gelu_f(v.z + li[2] + ljp[256]) * ww[2];
                part[jt] += gelu_f(v.w + li[3] + ljp[384]) * ww[3];
            }
        }
        #pragma unroll
        for (int jt = 0; jt < 2; jt++){
            part[jt] += __shfl_xor(part[jt], 16, 64);
            part[jt] += __shfl_xor(part[jt], 32, 64);
            if (q == 0) P[w][jt*16 + l15] = part[jt];
        }
        __syncthreads();
        if (tid < 32){
            float s = eh_b2[0];
            #pragma unroll
            for (int u = 0; u < 4; u++) s += P[u][tid];
            edge_out[(size_t)(b*128 + i)*128 + jq*32 + tid] = s;
        }
    }

    // ---- rel epilogue ----
    #pragma unroll
    for (int ct = 0; ct < 4; ct++){
        int cglob = (w*4 + ct)*16 + q*4;
        float li0 = linRs[cglob],   li1 = linRs[cglob+1];
        float li2 = linRs[cglob+2], li3 = linRs[cglob+3];
        int cs = cglob >> 5, qg2 = (cglob >> 3) & 3, u0 = cglob & 7;
        #pragma unroll
        for (int jt = 0; jt < 2; jt++){
            int jg = jq*32 + jt*16 + l15;
            const float* ljp = linJT + ((size_t)b*512 + 256 + cglob)*128 + jg;
            f32x4 v = aR[ct][jt];
            ushort g0 = f2bf(gelu_f(v.x + li0 + ljp[0]));
            ushort g1 = f2bf(gelu_f(v.y + li1 + ljp[128]));
            ushort g2 = f2bf(gelu_f(v.z + li2 + ljp[256]));
            ushort g3 = f2bf(gelu_f(v.w + li3 + ljp[384]));
            uint2 pk = make_uint2((uint)g0 | ((uint)g1 << 16),
                                  (uint)g2 | ((uint)g3 << 16));
            uint off = (uint)(((jt*8 + cs)*64 + qg2*16 + l15)*16 + u0*2);
            *(uint2*)((char*)Gs + off) = pk;
        }
    }
    __syncthreads();
    f32x4 acc2[2];
    acc2[0] = (f32x4){0.f,0.f,0.f,0.f};
    acc2[1] = (f32x4){0.f,0.f,0.f,0.f};
    #pragma unroll
    for (int cs = 0; cs < 8; cs++){
        s16x8 a2 = *(const s16x8*)(w2fR + (size_t)((cs*4 + w)*64 + lane)*8);
        #pragma unroll
        for (int jt = 0; jt < 2; jt++){
            s16x8 b2 = *(const s16x8*)(Gs + (size_t)((jt*8 + cs)*64 + lane)*8);
            acc2[jt] = __builtin_amdgcn_mfma_f32_16x16x32_bf16(a2, b2, acc2[jt], 0, 0, 0);
        }
    }
    #pragma unroll
    for (int jt = 0; jt < 2; jt++){
        int jl = jt*16 + l15;
        float vv[4] = {acc2[jt].x, acc2[jt].y, acc2[jt].z, acc2[jt].w};
        #pragma unroll
        for (int rg = 0; rg < 4; rg++){
            int r = w*16 + q*4 + rg;
            if (r < 50) Rel[jl*52 + r] = vv[rg] + rh_b2[r];
        }
    }
    __syncthreads();
    size_t obase = ((size_t)(b*128 + i)*128 + jq*32)*50;
    for (int s = tid; s < 1600; s += 256){
        int j = s / 50, r = s - j*50;
        rel_out[obase + s] = Rel[j*52 + r];
    }
}

extern "C" void kernel_launch(void* const* d_in, const int* in_sizes, int n_in,
                              void* d_out, int out_size, void* d_ws, size_t ws_size,
                              hipStream_t stream){
    const int*   obj_t     = (const int*)d_in[0];
    const int*   rel_t     = (const int*)d_in[1];
    const int*   t_in      = (const int*)d_in[2];
    const float* obj_emb   = (const float*)d_in[5];
    const float* rel_emb   = (const float*)d_in[6];
    const float* time_w1   = (const float*)d_in[7];
    const float* time_b1   = (const float*)d_in[8];
    const float* time_w2   = (const float*)d_in[9];
    const float* time_b2   = (const float*)d_in[10];
    const float* ln1_g     = (const float*)d_in[11];
    const float* ln1_b     = (const float*)d_in[12];
    const float* q_w       = (const float*)d_in[13];
    const float* q_b       = (const float*)d_in[14];
    const float* k_w       = (const float*)d_in[15];
    const float* k_b       = (const float*)d_in[16];
    const float* v_w       = (const float*)d_in[17];
    const float* v_b       = (const float*)d_in[18];
    const float* o_w       = (const float*)d_in[19];
    const float* o_b       = (const float*)d_in[20];
    const float* eb_w      = (const float*)d_in[21];
    const float* eb_b      = (const float*)d_in[22];
    const float* ln2_g     = (const float*)d_in[23];
    const float* ln2_b     = (const float*)d_in[24];
    const float* ff_w1     = (const float*)d_in[25];
    const float* ff_b1     = (const float*)d_in[26];
    const float* ff_w2     = (const float*)d_in[27];
    const float* ff_b2     = (const float*)d_in[28];
    const float* obj_hw    = (const float*)d_in[29];
    const float* obj_hb    = (const float*)d_in[30];
    const float* subj_w    = (const float*)d_in[31];
    const float* subj_b    = (const float*)d_in[32];
    const float* objp_w    = (const float*)d_in[33];
    const float* objp_b    = (const float*)d_in[34];
    const float* eh_w1     = (const float*)d_in[35];
    const float* eh_b1     = (const float*)d_in[36];
    const float* eh_w2     = (const float*)d_in[37];
    const float* eh_b2     = (const float*)d_in[38];
    const float* rh_w1     = (const float*)d_in[39];
    const float* rh_b1     = (const float*)d_in[40];
    const float* rh_w2     = (const float*)d_in[41];
    const float* rh_b2     = (const float*)d_in[42];

    float* out = (float*)d_out;
    float* obj_logits  = out;                 // 8*128*150
    float* edge_logits = out + 153600;        // 8*128*128
    float* rel_logits  = out + 284672;        // 8*128*128*50

    float* w = (float*)d_ws;
    float* temb    = w;  w += 2048;
    float* hbuf    = w;  w += 262144;
    float* relb    = w;  w += 2048;
    float* linI    = w;  w += 524288;         // [1024][512]
    float* linJT   = w;  w += 524288;         // [8][512][128]
    float* biascat = w;  w += 1024;
    float* qkvb    = w;  w += 4096;
    float* sob_b   = w;  w += 512;
    float* sjhob   = w;  w += 524288;         // [1024][512] fp32 subj|obj
    ushort* us     = (ushort*)w;
    ushort* qkv16  = us;  us += 786432;       // [1024][768]
    ushort* aob16  = us;  us += 262144;
    ushort* ff1b16 = us;  us += 1048576;
    ushort* hb16   = us;  us += 262144;
    ushort* sjhob16= us;  us += 524288;       // [1024][512]
    ushort* w3fE   = us;  us += 65536;
    ushort* w3fR   = us;  us += 65536;
    ushort* w2fR   = us;  us += 16384;
    ushort* wicatT = us;  us += 131072;
    ushort* wjT    = us;  us += 131072;
    ushort* objf   = us;  us += 262144;
    ushort* qkvT   = us;  us += 786432;
    ushort* oT     = us;  us += 262144;
    ushort* ff1T   = us;  us += 1048576;
    ushort* ff2T   = us;  us += 1048576;
    ushort* headT  = us;  us += 49152;
    ushort* sowT   = us;  us += 131072;       // [512][256] subj|objp

    k_prep_w<<<215, 256, 0, stream>>>(eh_w1, rh_w1, rh_w2, eh_b1, rh_b1,
                                      rel_emb, eb_w, eb_b,
                                      t_in, time_w1, time_b1, time_w2, time_b2,
                                      w3fE, w3fR, wjT, w2fR, wicatT, biascat,
                                      relb, temb);
    k_prep_bw<<<2650, 256, 0, stream>>>(q_w, k_w, v_w, o_w, ff_w1, ff_w2,
                                        obj_hw, subj_w, objp_w, q_b, k_b, v_b,
                                        subj_b, objp_b,
                                        obj_t, obj_emb, temb, hbuf,
                                        qkvT, oT, ff1T, ff2T, headT, sowT, qkvb, sob_b);

    for (int l = 0; l < LL; l++){
        k_lngemm<<<dim3(32,12), 256, 0, stream>>>(hbuf, ln1_g + l*DD, ln1_b + l*DD,
                qkvT + (size_t)l*196608, qkvb + l*768, qkv16, 768, 0);
        k_attn<<<256, 256, 0, stream>>>(qkv16, rel_t, relb + l*NREL_*HH, aob16);
        k_bgemm<16><<<dim3(64,4), 256, 0, stream>>>(aob16, oT + (size_t)l*65536,
                o_b + l*DD, hbuf, hbuf, nullptr, 256, 256, 256, 256, 256, 0, 0, 0, 0, 0);
        k_lngemm<<<dim3(32,16), 256, 0, stream>>>(hbuf, ln2_g + l*DD, ln2_b + l*DD,
                ff1T + (size_t)l*262144, ff_b1 + l*FFD, ff1b16, 1024, 1);
        k_bgemm<16><<<dim3(64,4), 256, 0, stream>>>(ff1b16, ff2T + (size_t)l*262144,
                ff_b2 + l*DD, hbuf, hbuf, hb16, 1024, 256, 1024, 1024, 256, 0, 0, 0, 0, 0);
    }

    // tail: head+sow merged; linI+linJT+prep_obj merged
    k_tail1<<<dim3(64,11), 256, 0, stream>>>(hb16, headT, sowT, obj_hb, sob_b,
                                             obj_logits, sjhob, sjhob16);
    k_tail2<<<1152, 256, 0, stream>>>(sjhob16, wicatT, wjT, biascat, sjhob,
                                      linI, linJT, objf);

    k_pair<<<4096, 256, 0, stream>>>(sjhob, linI, linJT, objf, w3fE, w3fR,
                                     w2fR, eh_w2, eh_b2, rh_b2,
                                     edge_logits, rel_logits);
}